// Round 7
// baseline (195.372 us; speedup 1.0000x reference)
//
#include <hip/hip_runtime.h>

#define B_  16
#define N_  128
#define NF_ 128
#define H_  128

typedef __attribute__((ext_vector_type(8))) short short8;
typedef __attribute__((ext_vector_type(4))) float floatx4;

__device__ __forceinline__ float silu_f(float x) {
    return x / (1.0f + __expf(-x));
}
__device__ __forceinline__ float sigm_f(float x) {
    return 1.0f / (1.0f + __expf(-x));
}
__device__ __forceinline__ unsigned short f2bf(float x) {
    union { float f; unsigned u; } v; v.f = x;
    unsigned r = (v.u + 0x7FFFu + ((v.u >> 16) & 1u)) >> 16;
    return (unsigned short)r;
}
__device__ __forceinline__ float bf2f(unsigned short s) {
    union { unsigned u; float f; } v; v.u = ((unsigned)s) << 16;
    return v.f;
}

// ---------------- k1: per-node precompute A = nf@We1[0:128], Bm = nf@We1[128:256]
__global__ __launch_bounds__(128) void k1_pre(const float* __restrict__ nf,
                                              const float* __restrict__ We1,
                                              float* __restrict__ A_ws,
                                              float* __restrict__ Bm_ws) {
    const int b  = blockIdx.x >> 4;
    const int r0 = (blockIdx.x & 15) << 3;
    const int h  = threadIdx.x;
    __shared__ float rows[8][128];
#pragma unroll
    for (int r = 0; r < 8; ++r)
        rows[r][h] = nf[((size_t)(b * N_ + r0 + r)) * NF_ + h];
    __syncthreads();
    float a[8], bm[8];
#pragma unroll
    for (int r = 0; r < 8; ++r) { a[r] = 0.f; bm[r] = 0.f; }
    for (int c = 0; c < NF_; ++c) {
        const float w1 = We1[c * H_ + h];
        const float w2 = We1[(NF_ + c) * H_ + h];
#pragma unroll
        for (int r = 0; r < 8; ++r) {
            const float x = rows[r][c];
            a[r]  = fmaf(x, w1, a[r]);
            bm[r] = fmaf(x, w2, bm[r]);
        }
    }
#pragma unroll
    for (int r = 0; r < 8; ++r) {
        A_ws [((size_t)(b * N_ + r0 + r)) * H_ + h] = a[r];
        Bm_ws[((size_t)(b * N_ + r0 + r)) * H_ + h] = bm[r];
    }
}

// ---------------- kC: Cinv[b] = 1/(sum_j valid - 1)
__global__ __launch_bounds__(64) void kC(const float* __restrict__ valid,
                                         float* __restrict__ Cinv) {
    const int b = blockIdx.x;
    const int t = threadIdx.x;
    float v = valid[b * N_ + t] + valid[b * N_ + 64 + t];
#pragma unroll
    for (int m = 32; m >= 1; m >>= 1) v += __shfl_down(v, m, 64);
    if (t == 0) Cinv[b] = 1.0f / (v - 1.0f);
}

// ---------------- k2: fused edge pipeline, wave-per-row, no in-loop barriers ----
// LDS layout (bytes); total 150464 < 160 KiB
#define OFF_BM    0                      // 128*136*2 = 34816  (Bm bf16, padded)
#define OFF_W2T   34816                  // 34816  (We2^T bf16)
#define OFF_WC1X  69632                  // 144*136*2 = 39168  ([Wc1^T | Wi | 0])
#define OFF_MB    108800                 // 34816  (8 per-wave 16x136 transpose slabs)
#define OFF_A     143616                 // 8*128 f32 = 4096
#define OFF_WC2   147712                 // 128 f32
#define OFF_POSJ  148224                 // 384 f32
#define OFF_VALJ  149760                 // 128 f32
#define OFF_POSI  150272                 // 24 f32 (pad 128)
#define OFF_VALI  150400                 // 8 f32 (pad 64)
#define SMEM_K2   150464

__global__ __launch_bounds__(512, 1) void k2_edge(
        const float* __restrict__ pos,
        const float* __restrict__ valid,
        const float* __restrict__ adj,
        const float* __restrict__ We1,
        const float* __restrict__ We2,
        const float* __restrict__ Wc1,
        const float* __restrict__ Wc2,
        const float* __restrict__ Wi,
        const float* __restrict__ A_ws,
        const float* __restrict__ Bm_ws,
        const float* __restrict__ Cinv,
        float* __restrict__ msg_ws,
        float* __restrict__ pos_out) {
    __shared__ __align__(16) char smem[SMEM_K2];
    unsigned short* BM   = (unsigned short*)(smem + OFF_BM);
    unsigned short* W2T  = (unsigned short*)(smem + OFF_W2T);
    unsigned short* WC1X = (unsigned short*)(smem + OFF_WC1X);
    unsigned short* MB   = (unsigned short*)(smem + OFF_MB);
    float* A_s  = (float*)(smem + OFF_A);
    float* wc2s = (float*)(smem + OFF_WC2);
    float* posj = (float*)(smem + OFF_POSJ);
    float* valj = (float*)(smem + OFF_VALJ);
    float* posi = (float*)(smem + OFF_POSI);
    float* vali = (float*)(smem + OFF_VALI);

    const int tid = threadIdx.x;
    const int b   = blockIdx.x >> 4;
    const int i0  = (blockIdx.x & 15) << 3;

    // ---- staging ----
    for (int q = tid; q < (N_ * H_) / 4; q += 512) {       // Bm -> bf16 LDS (pad 136)
        const int j  = q >> 5;
        const int ch = (q << 2) & 127;
        const float4 v = *(const float4*)(Bm_ws + ((size_t)(b * N_ + j)) * H_ + ch);
        ushort4 o;
        o.x = f2bf(v.x); o.y = f2bf(v.y); o.z = f2bf(v.z); o.w = f2bf(v.w);
        *(ushort4*)(BM + j * 136 + ch) = o;
    }
    for (int x = tid; x < H_ * H_; x += 512) {             // We2^T
        const int k = x >> 7, n = x & 127;
        W2T[n * 136 + k] = f2bf(We2[x]);
    }
    for (int x = tid; x < H_ * H_; x += 512) {             // Wc1^T (tiles 0..7)
        const int k = x >> 7, n = x & 127;
        WC1X[n * 136 + k] = f2bf(Wc1[x]);
    }
    if (tid < 128) WC1X[128 * 136 + tid] = f2bf(Wi[tid]);  // Wi column (tile 8, col 0)
    for (int x = tid; x < 15 * 136; x += 512)              // zero tile-8 cols 1..15
        WC1X[129 * 136 + x] = 0;
    for (int x = tid; x < 8 * H_; x += 512)
        A_s[x] = A_ws[((size_t)(b * N_ + i0)) * H_ + x];
    if (tid < 128) {
        wc2s[tid] = Wc2[tid];
        valj[tid] = valid[b * N_ + tid];
    }
    if (tid >= 128) posj[tid - 128] = pos[b * N_ * 3 + (tid - 128)];   // 384 floats
    if (tid < 24)   posi[tid] = pos[b * N_ * 3 + i0 * 3 + tid];
    if (tid >= 32 && tid < 40) vali[tid - 32] = valid[b * N_ + i0 + (tid - 32)];
    __syncthreads();

    const int w  = tid >> 6;
    const int l  = tid & 63;
    const int lr = l & 15;
    const int lg = l >> 4;
    const int i  = i0 + w;
    unsigned short* MBs = MB + w * (16 * 136);

    // ---- per-wave invariants in registers ----
    floatx4 ar[8];
#pragma unroll
    for (int ks = 0; ks < 4; ++ks) {
        ar[2 * ks]     = *(const floatx4*)(A_s + w * 128 + ks * 32 + lg * 8);
        ar[2 * ks + 1] = *(const floatx4*)(A_s + w * 128 + ks * 32 + lg * 8 + 4);
    }
    short8 wa[4], wb[4];   // We1 rows 256 (dist) / 257 (adj), bf16-packed per-lane slices
#pragma unroll
    for (int ks = 0; ks < 4; ++ks) {
        const floatx4 a0 = *(const floatx4*)(We1 + 256 * H_ + ks * 32 + lg * 8);
        const floatx4 a1 = *(const floatx4*)(We1 + 256 * H_ + ks * 32 + lg * 8 + 4);
        const floatx4 b0 = *(const floatx4*)(We1 + 257 * H_ + ks * 32 + lg * 8);
        const floatx4 b1 = *(const floatx4*)(We1 + 257 * H_ + ks * 32 + lg * 8 + 4);
#pragma unroll
        for (int e = 0; e < 4; ++e) {
            wa[ks][e]     = (short)f2bf(a0[e]);
            wa[ks][e + 4] = (short)f2bf(a1[e]);
            wb[ks][e]     = (short)f2bf(b0[e]);
            wb[ks][e + 4] = (short)f2bf(b1[e]);
        }
    }
    float wc2v[8];
#pragma unroll
    for (int nt = 0; nt < 8; ++nt) wc2v[nt] = wc2s[nt * 16 + lr];
    const float vi   = vali[w];
    const float pix  = posi[w * 3 + 0], piy = posi[w * 3 + 1], piz = posi[w * 3 + 2];
    const float cinv = Cinv[b];

    float msg[8] = {0.f, 0.f, 0.f, 0.f, 0.f, 0.f, 0.f, 0.f};
    float px = 0.f, py = 0.f, pz = 0.f;
    const floatx4 zf = {0.f, 0.f, 0.f, 0.f};

    for (int jc = 0; jc < 8; ++jc) {
        const int jj = jc * 16 + lr;
        const float adjv = adj[((size_t)(b * N_ + i)) * N_ + jj];
        const float vj   = valj[jj];
        const float vx = pix - posj[jj * 3 + 0];
        const float vy = piy - posj[jj * 3 + 1];
        const float vz = piz - posj[jj * 3 + 2];
        const float dist = vx * vx + vy * vy + vz * vz;
        const float vm   = vi * vj;
        const float rn   = 1.0f / fmaxf(sqrtf(dist), 1e-10f);
        const float vnx = vx * rn, vny = vy * rn, vnz = vz * rn;

        // ---- GEMM1: silu(edge preact) @ We2 ----
        short8 af[4];
#pragma unroll
        for (int ks = 0; ks < 4; ++ks) {
            const short8 bm8 = *(const short8*)(BM + jj * 136 + ks * 32 + lg * 8);
#pragma unroll
            for (int e = 0; e < 8; ++e) {
                const float pre = ar[2 * ks + (e >> 2)][e & 3]
                                + bf2f((unsigned short)bm8[e])
                                + dist * bf2f((unsigned short)wa[ks][e])
                                + adjv * bf2f((unsigned short)wb[ks][e]);
                af[ks][e] = (short)f2bf(silu_f(pre));
            }
        }
        floatx4 acc1[8];
#pragma unroll
        for (int nt = 0; nt < 8; ++nt) acc1[nt] = zf;
#pragma unroll
        for (int nt = 0; nt < 8; ++nt)
#pragma unroll
            for (int ks = 0; ks < 4; ++ks) {
                const short8 bf = *(const short8*)(W2T + (nt * 16 + lr) * 136 + ks * 32 + lg * 8);
                acc1[nt] = __builtin_amdgcn_mfma_f32_16x16x32_bf16(af[ks], bf, acc1[nt], 0, 0, 0);
            }
        // m = silu(.)  in place: lane holds edge lg*4+r, channel nt*16+lr
#pragma unroll
        for (int nt = 0; nt < 8; ++nt)
#pragma unroll
            for (int r = 0; r < 4; ++r)
                acc1[nt][r] = silu_f(acc1[nt][r]);

        // re-fragment m via per-wave LDS slab (no barrier: same-wave ordering)
#pragma unroll
        for (int nt = 0; nt < 8; ++nt)
#pragma unroll
            for (int r = 0; r < 4; ++r)
                MBs[(lg * 4 + r) * 136 + nt * 16 + lr] = f2bf(acc1[nt][r]);
        short8 af2[4];
#pragma unroll
        for (int ks = 0; ks < 4; ++ks)
            af2[ks] = *(const short8*)(MBs + lr * 136 + ks * 32 + lg * 8);

        // ---- GEMM2: m @ [Wc1 | Wi] (9 col-tiles) ----
        floatx4 acc2[9];
#pragma unroll
        for (int nt = 0; nt < 9; ++nt) acc2[nt] = zf;
#pragma unroll
        for (int nt = 0; nt < 9; ++nt)
#pragma unroll
            for (int ks = 0; ks < 4; ++ks) {
                const short8 bf = *(const short8*)(WC1X + (nt * 16 + lr) * 136 + ks * 32 + lg * 8);
                acc2[nt] = __builtin_amdgcn_mfma_f32_16x16x32_bf16(af2[ks], bf, acc2[nt], 0, 0, 0);
            }

        // gate e = sigmoid(m@Wi) (tile 8 col 0, lanes lr==0) and adj, per edge r
        float t4[4];
#pragma unroll
        for (int r = 0; r < 4; ++r) {
            const float ep  = __shfl(acc2[8][r], l & 48);
            const float ajr = __shfl(adjv, (l & 48) | (lg * 4 + r));
            t4[r] = sigm_f(ep) * ajr;
        }
        // message partial (stays in registers across chunks)
#pragma unroll
        for (int nt = 0; nt < 8; ++nt)
            msg[nt] += acc1[nt][0] * t4[0] + acc1[nt][1] * t4[1]
                     + acc1[nt][2] * t4[2] + acc1[nt][3] * t4[3];

        // phi = silu(y2) @ Wc2, reduce over channels (lr within 16-group)
        float ph[4] = {0.f, 0.f, 0.f, 0.f};
#pragma unroll
        for (int nt = 0; nt < 8; ++nt)
#pragma unroll
            for (int r = 0; r < 4; ++r)
                ph[r] = fmaf(silu_f(acc2[nt][r]), wc2v[nt], ph[r]);
#pragma unroll
        for (int msk = 1; msk <= 8; msk <<= 1)
#pragma unroll
            for (int r = 0; r < 4; ++r)
                ph[r] += __shfl_xor(ph[r], msk);
        // gather phi for this lane's own edge jj (group lr>>2, reg lr&3)
        const int src = ((lr >> 2) << 4) | lr;
        const float q0 = __shfl(ph[0], src), q1 = __shfl(ph[1], src);
        const float q2 = __shfl(ph[2], src), q3 = __shfl(ph[3], src);
        const int rr = lr & 3;
        const float phl = rr == 0 ? q0 : rr == 1 ? q1 : rr == 2 ? q2 : q3;
        const float pm = phl * vm;
        px = fmaf(vnx, pm, px); py = fmaf(vny, pm, py); pz = fmaf(vnz, pm, pz);
    }

    // ---- epilogue (register reductions, no LDS) ----
#pragma unroll
    for (int msk = 16; msk <= 32; msk <<= 1)
#pragma unroll
        for (int nt = 0; nt < 8; ++nt)
            msg[nt] += __shfl_xor(msg[nt], msk);
    if (l < 16) {
#pragma unroll
        for (int nt = 0; nt < 8; ++nt)
            msg_ws[((size_t)(b * N_ + i)) * H_ + nt * 16 + l] = msg[nt];
    }
#pragma unroll
    for (int msk = 1; msk <= 8; msk <<= 1) {
        px += __shfl_xor(px, msk);
        py += __shfl_xor(py, msk);
        pz += __shfl_xor(pz, msk);
    }
    if (l == 0) {
        const size_t o = ((size_t)(b * N_ + i)) * 3;
        pos_out[o + 0] = pos[o + 0] + cinv * px;
        pos_out[o + 1] = pos[o + 1] + cinv * py;
        pos_out[o + 2] = pos[o + 2] + cinv * pz;
    }
}

// ---------------- k3: node MLP ----------------
__global__ __launch_bounds__(128) void k3_node(
        const float* __restrict__ nf,
        const float* __restrict__ Wn1,
        const float* __restrict__ Wn2,
        const float* __restrict__ msg_ws,
        float* __restrict__ out) {
    const int b  = blockIdx.x >> 4;
    const int r0 = (blockIdx.x & 15) << 3;
    const int h  = threadIdx.x;
    __shared__ float in_s[8][256];
    __shared__ float t_s[8][128];
#pragma unroll
    for (int r = 0; r < 8; ++r) {
        in_s[r][h]       = nf[((size_t)(b * N_ + r0 + r)) * NF_ + h];
        in_s[r][128 + h] = msg_ws[((size_t)(b * N_ + r0 + r)) * H_ + h];
    }
    __syncthreads();
    float acc[8];
#pragma unroll
    for (int r = 0; r < 8; ++r) acc[r] = 0.f;
    for (int c = 0; c < 256; ++c) {
        const float wv = Wn1[c * H_ + h];
#pragma unroll
        for (int r = 0; r < 8; ++r) acc[r] = fmaf(in_s[r][c], wv, acc[r]);
    }
#pragma unroll
    for (int r = 0; r < 8; ++r) t_s[r][h] = silu_f(acc[r]);
    __syncthreads();
    float o[8];
#pragma unroll
    for (int r = 0; r < 8; ++r) o[r] = 0.f;
    for (int c = 0; c < 128; ++c) {
        const float wv = Wn2[c * NF_ + h];
#pragma unroll
        for (int r = 0; r < 8; ++r) o[r] = fmaf(t_s[r][c], wv, o[r]);
    }
#pragma unroll
    for (int r = 0; r < 8; ++r)
        out[((size_t)(b * N_ + r0 + r)) * NF_ + h] = in_s[r][h] + o[r];
}

extern "C" void kernel_launch(void* const* d_in, const int* in_sizes, int n_in,
                              void* d_out, int out_size, void* d_ws, size_t ws_size,
                              hipStream_t stream) {
    const float* node_feat = (const float*)d_in[0];
    const float* pos   = (const float*)d_in[1];
    const float* valid = (const float*)d_in[2];
    const float* adj   = (const float*)d_in[3];
    const float* We1   = (const float*)d_in[4];
    const float* We2   = (const float*)d_in[5];
    const float* Wc1   = (const float*)d_in[6];
    const float* Wc2   = (const float*)d_in[7];
    const float* Wn1   = (const float*)d_in[8];
    const float* Wn2   = (const float*)d_in[9];
    const float* Wi    = (const float*)d_in[10];

    float* out     = (float*)d_out;
    float* pos_out = out + (size_t)B_ * N_ * NF_;

    const size_t node_elems = (size_t)B_ * N_ * H_;
    if (ws_size < (3 * node_elems + B_) * sizeof(float)) return;
    float* A_ws   = (float*)d_ws;
    float* Bm_ws  = A_ws + node_elems;
    float* msg_ws = Bm_ws + node_elems;
    float* Cinv   = msg_ws + node_elems;

    k1_pre<<<B_ * 16, 128, 0, stream>>>(node_feat, We1, A_ws, Bm_ws);
    kC<<<B_, 64, 0, stream>>>(valid, Cinv);
    k2_edge<<<B_ * 16, 512, 0, stream>>>(pos, valid, adj, We1, We2, Wc1, Wc2, Wi,
                                         A_ws, Bm_ws, Cinv, msg_ws, pos_out);
    k3_node<<<B_ * 16, 128, 0, stream>>>(node_feat, Wn1, Wn2, msg_ws, out);
}

// Round 8
// 160.733 us; speedup vs baseline: 1.2155x; 1.2155x over previous
//
#include <hip/hip_runtime.h>
#include <hip/hip_bf16.h>

#define B_  16
#define N_  128
#define NF_ 128
#define H_  128

typedef __attribute__((ext_vector_type(8))) short short8;
typedef __attribute__((ext_vector_type(4))) float floatx4;

__device__ __forceinline__ float silu_f(float x) {
    // x * sigmoid(x) with HW rcp (no f32 div sequence)
    return x * __builtin_amdgcn_rcpf(1.0f + __expf(-x));
}
__device__ __forceinline__ float sigm_f(float x) {
    return __builtin_amdgcn_rcpf(1.0f + __expf(-x));
}
__device__ __forceinline__ unsigned short f2bf(float x) {   // staging path (RNE)
    union { float f; unsigned u; } v; v.f = x;
    unsigned r = (v.u + 0x7FFFu + ((v.u >> 16) & 1u)) >> 16;
    return (unsigned short)r;
}
__device__ __forceinline__ short f2bf_fast(float x) {       // hot path: native cvt
    union { __hip_bfloat16 h; short s; } u;
    u.h = __float2bfloat16(x);
    return u.s;
}
__device__ __forceinline__ float bf2f(unsigned short s) {
    union { unsigned u; float f; } v; v.u = ((unsigned)s) << 16;
    return v.f;
}

// ---------------- k1: per-node precompute A = nf@We1[0:128], Bm = nf@We1[128:256]
__global__ __launch_bounds__(128) void k1_pre(const float* __restrict__ nf,
                                              const float* __restrict__ We1,
                                              float* __restrict__ A_ws,
                                              float* __restrict__ Bm_ws) {
    const int b  = blockIdx.x >> 4;
    const int r0 = (blockIdx.x & 15) << 3;
    const int h  = threadIdx.x;
    __shared__ float rows[8][128];
#pragma unroll
    for (int r = 0; r < 8; ++r)
        rows[r][h] = nf[((size_t)(b * N_ + r0 + r)) * NF_ + h];
    __syncthreads();
    float a[8], bm[8];
#pragma unroll
    for (int r = 0; r < 8; ++r) { a[r] = 0.f; bm[r] = 0.f; }
    for (int c = 0; c < NF_; ++c) {
        const float w1 = We1[c * H_ + h];
        const float w2 = We1[(NF_ + c) * H_ + h];
#pragma unroll
        for (int r = 0; r < 8; ++r) {
            const float x = rows[r][c];
            a[r]  = fmaf(x, w1, a[r]);
            bm[r] = fmaf(x, w2, bm[r]);
        }
    }
#pragma unroll
    for (int r = 0; r < 8; ++r) {
        A_ws [((size_t)(b * N_ + r0 + r)) * H_ + h] = a[r];
        Bm_ws[((size_t)(b * N_ + r0 + r)) * H_ + h] = bm[r];
    }
}

// ---------------- kC: Cinv[b] = 1/(sum_j valid - 1)
__global__ __launch_bounds__(64) void kC(const float* __restrict__ valid,
                                         float* __restrict__ Cinv) {
    const int b = blockIdx.x;
    const int t = threadIdx.x;
    float v = valid[b * N_ + t] + valid[b * N_ + 64 + t];
#pragma unroll
    for (int m = 32; m >= 1; m >>= 1) v += __shfl_down(v, m, 64);
    if (t == 0) Cinv[b] = 1.0f / (v - 1.0f);
}

// ---------------- k2: fused edge pipeline, wave-per-row, no in-loop barriers ----
// LDS layout (bytes); total 150464 < 160 KiB
#define OFF_BM    0                      // 128*136*2 = 34816  (Bm bf16, padded)
#define OFF_W2T   34816                  // 34816  (We2^T bf16)
#define OFF_WC1X  69632                  // 144*136*2 = 39168  ([Wc1^T | Wi | 0])
#define OFF_MB    108800                 // 34816  (8 per-wave 16x136 transpose slabs)
#define OFF_A     143616                 // 8*128 f32 = 4096
#define OFF_WC2   147712                 // 128 f32
#define OFF_POSJ  148224                 // 384 f32
#define OFF_VALJ  149760                 // 128 f32
#define OFF_POSI  150272                 // 24 f32 (pad 128)
#define OFF_VALI  150400                 // 8 f32 (pad 64)
#define SMEM_K2   150464

__global__ __launch_bounds__(512, 2) void k2_edge(
        const float* __restrict__ pos,
        const float* __restrict__ valid,
        const float* __restrict__ adj,
        const float* __restrict__ We1,
        const float* __restrict__ We2,
        const float* __restrict__ Wc1,
        const float* __restrict__ Wc2,
        const float* __restrict__ Wi,
        const float* __restrict__ A_ws,
        const float* __restrict__ Bm_ws,
        const float* __restrict__ Cinv,
        float* __restrict__ msg_ws,
        float* __restrict__ pos_out) {
    __shared__ __align__(16) char smem[SMEM_K2];
    unsigned short* BM   = (unsigned short*)(smem + OFF_BM);
    unsigned short* W2T  = (unsigned short*)(smem + OFF_W2T);
    unsigned short* WC1X = (unsigned short*)(smem + OFF_WC1X);
    unsigned short* MB   = (unsigned short*)(smem + OFF_MB);
    float* A_s  = (float*)(smem + OFF_A);
    float* wc2s = (float*)(smem + OFF_WC2);
    float* posj = (float*)(smem + OFF_POSJ);
    float* valj = (float*)(smem + OFF_VALJ);
    float* posi = (float*)(smem + OFF_POSI);
    float* vali = (float*)(smem + OFF_VALI);

    const int tid = threadIdx.x;
    const int b   = blockIdx.x >> 4;
    const int i0  = (blockIdx.x & 15) << 3;

    // ---- staging ----
    for (int q = tid; q < (N_ * H_) / 4; q += 512) {       // Bm -> bf16 LDS (pad 136)
        const int j  = q >> 5;
        const int ch = (q << 2) & 127;
        const float4 v = *(const float4*)(Bm_ws + ((size_t)(b * N_ + j)) * H_ + ch);
        ushort4 o;
        o.x = f2bf(v.x); o.y = f2bf(v.y); o.z = f2bf(v.z); o.w = f2bf(v.w);
        *(ushort4*)(BM + j * 136 + ch) = o;
    }
    for (int x = tid; x < H_ * H_; x += 512) {             // We2^T
        const int k = x >> 7, n = x & 127;
        W2T[n * 136 + k] = f2bf(We2[x]);
    }
    for (int x = tid; x < H_ * H_; x += 512) {             // Wc1^T (tiles 0..7)
        const int k = x >> 7, n = x & 127;
        WC1X[n * 136 + k] = f2bf(Wc1[x]);
    }
    if (tid < 128) WC1X[128 * 136 + tid] = f2bf(Wi[tid]);  // Wi column (tile 8, col 0)
    for (int x = tid; x < 15 * 136; x += 512)              // zero rows 129..143
        WC1X[129 * 136 + x] = 0;
    for (int x = tid; x < 8 * H_; x += 512)
        A_s[x] = A_ws[((size_t)(b * N_ + i0)) * H_ + x];
    if (tid < 128) {
        wc2s[tid] = Wc2[tid];
        valj[tid] = valid[b * N_ + tid];
    }
    if (tid >= 128) posj[tid - 128] = pos[b * N_ * 3 + (tid - 128)];   // 384 floats
    if (tid < 24)   posi[tid] = pos[b * N_ * 3 + i0 * 3 + tid];
    if (tid >= 32 && tid < 40) vali[tid - 32] = valid[b * N_ + i0 + (tid - 32)];
    __syncthreads();

    const int w  = tid >> 6;
    const int l  = tid & 63;
    const int lr = l & 15;
    const int lg = l >> 4;
    const int i  = i0 + w;
    unsigned short* MBs = MB + w * (16 * 136);

    // ---- per-wave invariants in registers (bf16-packed to control VGPR) ----
    short8 aw[4];          // A-row slice of this wave's i
#pragma unroll
    for (int ks = 0; ks < 4; ++ks) {
        const floatx4 a0 = *(const floatx4*)(A_s + w * 128 + ks * 32 + lg * 8);
        const floatx4 a1 = *(const floatx4*)(A_s + w * 128 + ks * 32 + lg * 8 + 4);
#pragma unroll
        for (int e = 0; e < 4; ++e) {
            aw[ks][e]     = f2bf_fast(a0[e]);
            aw[ks][e + 4] = f2bf_fast(a1[e]);
        }
    }
    short8 wa[4], wb[4];   // We1 rows 256 (dist) / 257 (adj)
#pragma unroll
    for (int ks = 0; ks < 4; ++ks) {
        const floatx4 a0 = *(const floatx4*)(We1 + 256 * H_ + ks * 32 + lg * 8);
        const floatx4 a1 = *(const floatx4*)(We1 + 256 * H_ + ks * 32 + lg * 8 + 4);
        const floatx4 b0 = *(const floatx4*)(We1 + 257 * H_ + ks * 32 + lg * 8);
        const floatx4 b1 = *(const floatx4*)(We1 + 257 * H_ + ks * 32 + lg * 8 + 4);
#pragma unroll
        for (int e = 0; e < 4; ++e) {
            wa[ks][e]     = f2bf_fast(a0[e]);
            wa[ks][e + 4] = f2bf_fast(a1[e]);
            wb[ks][e]     = f2bf_fast(b0[e]);
            wb[ks][e + 4] = f2bf_fast(b1[e]);
        }
    }
    float wc2v[8];
#pragma unroll
    for (int nt = 0; nt < 8; ++nt) wc2v[nt] = wc2s[nt * 16 + lr];
    const float vi   = vali[w];
    const float pix  = posi[w * 3 + 0], piy = posi[w * 3 + 1], piz = posi[w * 3 + 2];
    const float cinv = Cinv[b];

    float msg[8] = {0.f, 0.f, 0.f, 0.f, 0.f, 0.f, 0.f, 0.f};
    float px = 0.f, py = 0.f, pz = 0.f;
    const floatx4 zf = {0.f, 0.f, 0.f, 0.f};

    for (int jc = 0; jc < 8; ++jc) {
        const int jj = jc * 16 + lr;
        const float adjv = adj[((size_t)(b * N_ + i)) * N_ + jj];
        const float vj   = valj[jj];
        const float vx = pix - posj[jj * 3 + 0];
        const float vy = piy - posj[jj * 3 + 1];
        const float vz = piz - posj[jj * 3 + 2];
        const float dist = vx * vx + vy * vy + vz * vz;
        const float vm   = vi * vj;
        const float rn   = __builtin_amdgcn_rcpf(fmaxf(sqrtf(dist), 1e-10f));
        const float vnx = vx * rn, vny = vy * rn, vnz = vz * rn;

        // ---- GEMM1: silu(edge preact) @ We2 ----
        short8 af[4];
#pragma unroll
        for (int ks = 0; ks < 4; ++ks) {
            const short8 bm8 = *(const short8*)(BM + jj * 136 + ks * 32 + lg * 8);
#pragma unroll
            for (int e = 0; e < 8; ++e) {
                const float pre = bf2f((unsigned short)aw[ks][e])
                                + bf2f((unsigned short)bm8[e])
                                + dist * bf2f((unsigned short)wa[ks][e])
                                + adjv * bf2f((unsigned short)wb[ks][e]);
                af[ks][e] = f2bf_fast(silu_f(pre));
            }
        }
        floatx4 acc1[8];
#pragma unroll
        for (int nt = 0; nt < 8; ++nt) acc1[nt] = zf;
#pragma unroll
        for (int nt = 0; nt < 8; ++nt)
#pragma unroll
            for (int ks = 0; ks < 4; ++ks) {
                const short8 bf = *(const short8*)(W2T + (nt * 16 + lr) * 136 + ks * 32 + lg * 8);
                acc1[nt] = __builtin_amdgcn_mfma_f32_16x16x32_bf16(af[ks], bf, acc1[nt], 0, 0, 0);
            }
        // m = silu(.)  in place: lane holds edge lg*4+r, channel nt*16+lr
#pragma unroll
        for (int nt = 0; nt < 8; ++nt)
#pragma unroll
            for (int r = 0; r < 4; ++r)
                acc1[nt][r] = silu_f(acc1[nt][r]);

        // re-fragment m via per-wave LDS slab (no barrier: same-wave ordering)
#pragma unroll
        for (int nt = 0; nt < 8; ++nt)
#pragma unroll
            for (int r = 0; r < 4; ++r)
                MBs[(lg * 4 + r) * 136 + nt * 16 + lr] = (unsigned short)f2bf_fast(acc1[nt][r]);
        short8 af2[4];
#pragma unroll
        for (int ks = 0; ks < 4; ++ks)
            af2[ks] = *(const short8*)(MBs + lr * 136 + ks * 32 + lg * 8);

        // ---- GEMM2: m @ [Wc1 | Wi] (9 col-tiles) ----
        floatx4 acc2[9];
#pragma unroll
        for (int nt = 0; nt < 9; ++nt) acc2[nt] = zf;
#pragma unroll
        for (int nt = 0; nt < 9; ++nt)
#pragma unroll
            for (int ks = 0; ks < 4; ++ks) {
                const short8 bf = *(const short8*)(WC1X + (nt * 16 + lr) * 136 + ks * 32 + lg * 8);
                acc2[nt] = __builtin_amdgcn_mfma_f32_16x16x32_bf16(af2[ks], bf, acc2[nt], 0, 0, 0);
            }

        // gate e = sigmoid(m@Wi) (tile 8 col 0) and adj, per edge r
        float t4[4];
#pragma unroll
        for (int r = 0; r < 4; ++r) {
            const float ep  = __shfl(acc2[8][r], l & 48);
            const float ajr = __shfl(adjv, (l & 48) | (lg * 4 + r));
            t4[r] = sigm_f(ep) * ajr;
        }
        // message partial (stays in registers across chunks)
#pragma unroll
        for (int nt = 0; nt < 8; ++nt)
            msg[nt] += acc1[nt][0] * t4[0] + acc1[nt][1] * t4[1]
                     + acc1[nt][2] * t4[2] + acc1[nt][3] * t4[3];

        // phi = silu(y2) @ Wc2, reduce over channels
        float ph[4] = {0.f, 0.f, 0.f, 0.f};
#pragma unroll
        for (int nt = 0; nt < 8; ++nt)
#pragma unroll
            for (int r = 0; r < 4; ++r)
                ph[r] = fmaf(silu_f(acc2[nt][r]), wc2v[nt], ph[r]);
#pragma unroll
        for (int msk = 1; msk <= 8; msk <<= 1)
#pragma unroll
            for (int r = 0; r < 4; ++r)
                ph[r] += __shfl_xor(ph[r], msk);
        // gather phi for this lane's own edge jj
        const int src = ((lr >> 2) << 4) | lr;
        const float q0 = __shfl(ph[0], src), q1 = __shfl(ph[1], src);
        const float q2 = __shfl(ph[2], src), q3 = __shfl(ph[3], src);
        const int rr = lr & 3;
        const float phl = rr == 0 ? q0 : rr == 1 ? q1 : rr == 2 ? q2 : q3;
        const float pm = phl * vm;
        px = fmaf(vnx, pm, px); py = fmaf(vny, pm, py); pz = fmaf(vnz, pm, pz);
    }

    // ---- epilogue (register reductions, no LDS) ----
#pragma unroll
    for (int msk = 16; msk <= 32; msk <<= 1)
#pragma unroll
        for (int nt = 0; nt < 8; ++nt)
            msg[nt] += __shfl_xor(msg[nt], msk);
    if (l < 16) {
#pragma unroll
        for (int nt = 0; nt < 8; ++nt)
            msg_ws[((size_t)(b * N_ + i)) * H_ + nt * 16 + l] = msg[nt];
    }
#pragma unroll
    for (int msk = 1; msk <= 8; msk <<= 1) {
        px += __shfl_xor(px, msk);
        py += __shfl_xor(py, msk);
        pz += __shfl_xor(pz, msk);
    }
    if (l == 0) {
        const size_t o = ((size_t)(b * N_ + i)) * 3;
        pos_out[o + 0] = pos[o + 0] + cinv * px;
        pos_out[o + 1] = pos[o + 1] + cinv * py;
        pos_out[o + 2] = pos[o + 2] + cinv * pz;
    }
}

// ---------------- k3: node MLP ----------------
__global__ __launch_bounds__(128) void k3_node(
        const float* __restrict__ nf,
        const float* __restrict__ Wn1,
        const float* __restrict__ Wn2,
        const float* __restrict__ msg_ws,
        float* __restrict__ out) {
    const int b  = blockIdx.x >> 4;
    const int r0 = (blockIdx.x & 15) << 3;
    const int h  = threadIdx.x;
    __shared__ float in_s[8][256];
    __shared__ float t_s[8][128];
#pragma unroll
    for (int r = 0; r < 8; ++r) {
        in_s[r][h]       = nf[((size_t)(b * N_ + r0 + r)) * NF_ + h];
        in_s[r][128 + h] = msg_ws[((size_t)(b * N_ + r0 + r)) * H_ + h];
    }
    __syncthreads();
    float acc[8];
#pragma unroll
    for (int r = 0; r < 8; ++r) acc[r] = 0.f;
    for (int c = 0; c < 256; ++c) {
        const float wv = Wn1[c * H_ + h];
#pragma unroll
        for (int r = 0; r < 8; ++r) acc[r] = fmaf(in_s[r][c], wv, acc[r]);
    }
#pragma unroll
    for (int r = 0; r < 8; ++r) t_s[r][h] = silu_f(acc[r]);
    __syncthreads();
    float o[8];
#pragma unroll
    for (int r = 0; r < 8; ++r) o[r] = 0.f;
    for (int c = 0; c < 128; ++c) {
        const float wv = Wn2[c * NF_ + h];
#pragma unroll
        for (int r = 0; r < 8; ++r) o[r] = fmaf(t_s[r][c], wv, o[r]);
    }
#pragma unroll
    for (int r = 0; r < 8; ++r)
        out[((size_t)(b * N_ + r0 + r)) * NF_ + h] = in_s[r][h] + o[r];
}

extern "C" void kernel_launch(void* const* d_in, const int* in_sizes, int n_in,
                              void* d_out, int out_size, void* d_ws, size_t ws_size,
                              hipStream_t stream) {
    const float* node_feat = (const float*)d_in[0];
    const float* pos   = (const float*)d_in[1];
    const float* valid = (const float*)d_in[2];
    const float* adj   = (const float*)d_in[3];
    const float* We1   = (const float*)d_in[4];
    const float* We2   = (const float*)d_in[5];
    const float* Wc1   = (const float*)d_in[6];
    const float* Wc2   = (const float*)d_in[7];
    const float* Wn1   = (const float*)d_in[8];
    const float* Wn2   = (const float*)d_in[9];
    const float* Wi    = (const float*)d_in[10];

    float* out     = (float*)d_out;
    float* pos_out = out + (size_t)B_ * N_ * NF_;

    const size_t node_elems = (size_t)B_ * N_ * H_;
    if (ws_size < (3 * node_elems + B_) * sizeof(float)) return;
    float* A_ws   = (float*)d_ws;
    float* Bm_ws  = A_ws + node_elems;
    float* msg_ws = Bm_ws + node_elems;
    float* Cinv   = msg_ws + node_elems;

    k1_pre<<<B_ * 16, 128, 0, stream>>>(node_feat, We1, A_ws, Bm_ws);
    kC<<<B_, 64, 0, stream>>>(valid, Cinv);
    k2_edge<<<B_ * 16, 512, 0, stream>>>(pos, valid, adj, We1, We2, Wc1, Wc2, Wi,
                                         A_ws, Bm_ws, Cinv, msg_ws, pos_out);
    k3_node<<<B_ * 16, 128, 0, stream>>>(node_feat, Wn1, Wn2, msg_ws, out);
}

// Round 9
// 82.782 us; speedup vs baseline: 2.3601x; 1.9417x over previous
//
#include <hip/hip_runtime.h>
#include <hip/hip_bf16.h>

#define B_  16
#define N_  128
#define NF_ 128
#define H_  128

typedef __attribute__((ext_vector_type(8))) short short8;
typedef __attribute__((ext_vector_type(4))) float floatx4;

__device__ __forceinline__ float silu_f(float x) {
    return x * __builtin_amdgcn_rcpf(1.0f + __expf(-x));
}
__device__ __forceinline__ float sigm_f(float x) {
    return __builtin_amdgcn_rcpf(1.0f + __expf(-x));
}
__device__ __forceinline__ unsigned short f2bf(float x) {   // staging path (RNE)
    union { float f; unsigned u; } v; v.f = x;
    unsigned r = (v.u + 0x7FFFu + ((v.u >> 16) & 1u)) >> 16;
    return (unsigned short)r;
}
__device__ __forceinline__ short f2bf_fast(float x) {       // hot path: native cvt
    union { __hip_bfloat16 h; short s; } u;
    u.h = __float2bfloat16(x);
    return u.s;
}
__device__ __forceinline__ float bf2f(unsigned short s) {
    union { unsigned u; float f; } v; v.u = ((unsigned)s) << 16;
    return v.f;
}

// ---------------- k1: per-node precompute A = nf@We1[0:128], Bm = nf@We1[128:256]
__global__ __launch_bounds__(128) void k1_pre(const float* __restrict__ nf,
                                              const float* __restrict__ We1,
                                              float* __restrict__ A_ws,
                                              float* __restrict__ Bm_ws) {
    const int b  = blockIdx.x >> 4;
    const int r0 = (blockIdx.x & 15) << 3;
    const int h  = threadIdx.x;
    __shared__ float rows[8][128];
#pragma unroll
    for (int r = 0; r < 8; ++r)
        rows[r][h] = nf[((size_t)(b * N_ + r0 + r)) * NF_ + h];
    __syncthreads();
    float a[8], bm[8];
#pragma unroll
    for (int r = 0; r < 8; ++r) { a[r] = 0.f; bm[r] = 0.f; }
    for (int c = 0; c < NF_; ++c) {
        const float w1 = We1[c * H_ + h];
        const float w2 = We1[(NF_ + c) * H_ + h];
#pragma unroll
        for (int r = 0; r < 8; ++r) {
            const float x = rows[r][c];
            a[r]  = fmaf(x, w1, a[r]);
            bm[r] = fmaf(x, w2, bm[r]);
        }
    }
#pragma unroll
    for (int r = 0; r < 8; ++r) {
        A_ws [((size_t)(b * N_ + r0 + r)) * H_ + h] = a[r];
        Bm_ws[((size_t)(b * N_ + r0 + r)) * H_ + h] = bm[r];
    }
}

// ---------------- kC: Cinv[b] = 1/(sum_j valid - 1)
__global__ __launch_bounds__(64) void kC(const float* __restrict__ valid,
                                         float* __restrict__ Cinv) {
    const int b = blockIdx.x;
    const int t = threadIdx.x;
    float v = valid[b * N_ + t] + valid[b * N_ + 64 + t];
#pragma unroll
    for (int m = 32; m >= 1; m >>= 1) v += __shfl_down(v, m, 64);
    if (t == 0) Cinv[b] = 1.0f / (v - 1.0f);
}

// ---------------- k2: fused edge pipeline, wave-per-row, register-lean ----------
// LDS layout (bytes); total 149088 < 160 KiB
#define OFF_BM    0                      // 128*136*2 = 34816  (Bm bf16, padded)
#define OFF_W2T   34816                  // 34816  (We2^T bf16)
#define OFF_WC1X  69632                  // 144*136*2 = 39168  ([Wc1^T | Wi | 0])
#define OFF_MB    108800                 // 34816  (8 per-wave 16x136 transpose slabs)
#define OFF_AW    143616                 // 8*136*2 = 2176  (A rows, bf16)
#define OFF_WAB   145792                 // 2*136*2 = 544   (We1 rows 256/257, bf16)
#define OFF_WC2   146336                 // 128 f32 = 512
#define OFF_POSJ  146848                 // 384 f32 = 1536
#define OFF_VALJ  148384                 // 128 f32 = 512
#define OFF_POSI  148896                 // 24 f32 (pad 128)
#define OFF_VALI  149024                 // 8 f32 (pad 64)
#define SMEM_K2   149088

__global__ __launch_bounds__(512, 2) void k2_edge(
        const float* __restrict__ pos,
        const float* __restrict__ valid,
        const float* __restrict__ adj,
        const float* __restrict__ We1,
        const float* __restrict__ We2,
        const float* __restrict__ Wc1,
        const float* __restrict__ Wc2,
        const float* __restrict__ Wi,
        const float* __restrict__ A_ws,
        const float* __restrict__ Bm_ws,
        const float* __restrict__ Cinv,
        float* __restrict__ msg_ws,
        float* __restrict__ pos_out) {
    __shared__ __align__(16) char smem[SMEM_K2];
    unsigned short* BM   = (unsigned short*)(smem + OFF_BM);
    unsigned short* W2T  = (unsigned short*)(smem + OFF_W2T);
    unsigned short* WC1X = (unsigned short*)(smem + OFF_WC1X);
    unsigned short* MB   = (unsigned short*)(smem + OFF_MB);
    unsigned short* AW   = (unsigned short*)(smem + OFF_AW);
    unsigned short* WAB  = (unsigned short*)(smem + OFF_WAB);
    float* wc2s = (float*)(smem + OFF_WC2);
    float* posj = (float*)(smem + OFF_POSJ);
    float* valj = (float*)(smem + OFF_VALJ);
    float* posi = (float*)(smem + OFF_POSI);
    float* vali = (float*)(smem + OFF_VALI);

    const int tid = threadIdx.x;
    const int b   = blockIdx.x >> 4;
    const int i0  = (blockIdx.x & 15) << 3;

    // ---- staging ----
    for (int q = tid; q < (N_ * H_) / 4; q += 512) {       // Bm -> bf16 LDS (pad 136)
        const int j  = q >> 5;
        const int ch = (q << 2) & 127;
        const float4 v = *(const float4*)(Bm_ws + ((size_t)(b * N_ + j)) * H_ + ch);
        ushort4 o;
        o.x = f2bf(v.x); o.y = f2bf(v.y); o.z = f2bf(v.z); o.w = f2bf(v.w);
        *(ushort4*)(BM + j * 136 + ch) = o;
    }
    for (int x = tid; x < H_ * H_; x += 512) {             // We2^T
        const int k = x >> 7, n = x & 127;
        W2T[n * 136 + k] = f2bf(We2[x]);
    }
    for (int x = tid; x < H_ * H_; x += 512) {             // Wc1^T (tiles 0..7)
        const int k = x >> 7, n = x & 127;
        WC1X[n * 136 + k] = f2bf(Wc1[x]);
    }
    if (tid < 128) WC1X[128 * 136 + tid] = f2bf(Wi[tid]);  // Wi column (tile 8, col 0)
    for (int x = tid; x < 15 * 136; x += 512)              // zero rows 129..143
        WC1X[129 * 136 + x] = 0;
    for (int x = tid; x < 8 * H_; x += 512)                // A rows -> bf16
        AW[(x >> 7) * 136 + (x & 127)] =
            f2bf(A_ws[((size_t)(b * N_ + i0 + (x >> 7))) * H_ + (x & 127)]);
    if (tid < 256)                                          // We1 rows 256/257 -> bf16
        WAB[(tid >> 7) * 136 + (tid & 127)] = f2bf(We1[(256 + (tid >> 7)) * H_ + (tid & 127)]);
    if (tid < 128) {
        wc2s[tid] = Wc2[tid];
        valj[tid] = valid[b * N_ + tid];
    }
    if (tid >= 128) posj[tid - 128] = pos[b * N_ * 3 + (tid - 128)];   // 384 floats
    if (tid < 24)   posi[tid] = pos[b * N_ * 3 + i0 * 3 + tid];
    if (tid >= 32 && tid < 40) vali[tid - 32] = valid[b * N_ + i0 + (tid - 32)];
    __syncthreads();

    const int w  = tid >> 6;
    const int l  = tid & 63;
    const int lr = l & 15;
    const int lg = l >> 4;
    const int i  = i0 + w;
    unsigned short* MBs = MB + w * (16 * 136);

    float wc2v[8];
#pragma unroll
    for (int nt = 0; nt < 8; ++nt) wc2v[nt] = wc2s[nt * 16 + lr];
    const float vi   = vali[w];
    const float pix  = posi[w * 3 + 0], piy = posi[w * 3 + 1], piz = posi[w * 3 + 2];
    const float cinv = Cinv[b];

    float msg[8] = {0.f, 0.f, 0.f, 0.f, 0.f, 0.f, 0.f, 0.f};
    float px = 0.f, py = 0.f, pz = 0.f;
    const floatx4 zf = {0.f, 0.f, 0.f, 0.f};

    for (int jc = 0; jc < 8; ++jc) {
        const int jj = jc * 16 + lr;
        const float adjv = adj[((size_t)(b * N_ + i)) * N_ + jj];
        const float vj   = valj[jj];
        const float vx = pix - posj[jj * 3 + 0];
        const float vy = piy - posj[jj * 3 + 1];
        const float vz = piz - posj[jj * 3 + 2];
        const float dist = vx * vx + vy * vy + vz * vz;
        const float vm   = vi * vj;
        const float rn   = __builtin_amdgcn_rcpf(fmaxf(sqrtf(dist), 1e-10f));
        const float vnx = vx * rn, vny = vy * rn, vnz = vz * rn;

        // ---- GEMM1: silu(edge preact) @ We2 ----
        short8 af[4];
#pragma unroll
        for (int ks = 0; ks < 4; ++ks) {
            const int co = ks * 32 + lg * 8;
            const short8 bm8 = *(const short8*)(BM + jj * 136 + co);
            const short8 aw8 = *(const short8*)(AW + w * 136 + co);
            const short8 wa8 = *(const short8*)(WAB + co);
            const short8 wb8 = *(const short8*)(WAB + 136 + co);
#pragma unroll
            for (int e = 0; e < 8; ++e) {
                const float pre = bf2f((unsigned short)aw8[e])
                                + bf2f((unsigned short)bm8[e])
                                + dist * bf2f((unsigned short)wa8[e])
                                + adjv * bf2f((unsigned short)wb8[e]);
                af[ks][e] = f2bf_fast(silu_f(pre));
            }
        }
        floatx4 acc1[8];
#pragma unroll
        for (int nt = 0; nt < 8; ++nt) acc1[nt] = zf;
#pragma unroll
        for (int nt = 0; nt < 8; ++nt)
#pragma unroll
            for (int ks = 0; ks < 4; ++ks) {
                const short8 bf = *(const short8*)(W2T + (nt * 16 + lr) * 136 + ks * 32 + lg * 8);
                acc1[nt] = __builtin_amdgcn_mfma_f32_16x16x32_bf16(af[ks], bf, acc1[nt], 0, 0, 0);
            }
        // m = silu(.) in place: lane holds edge lg*4+r, channel nt*16+lr
#pragma unroll
        for (int nt = 0; nt < 8; ++nt)
#pragma unroll
            for (int r = 0; r < 4; ++r)
                acc1[nt][r] = silu_f(acc1[nt][r]);

        // re-fragment m via per-wave LDS slab (no barrier: same-wave ordering)
#pragma unroll
        for (int nt = 0; nt < 8; ++nt)
#pragma unroll
            for (int r = 0; r < 4; ++r)
                MBs[(lg * 4 + r) * 136 + nt * 16 + lr] = (unsigned short)f2bf_fast(acc1[nt][r]);
        short8 af2[4];
#pragma unroll
        for (int ks = 0; ks < 4; ++ks)
            af2[ks] = *(const short8*)(MBs + lr * 136 + ks * 32 + lg * 8);

        // ---- gate tile first: e-preact = m @ Wi (WC1X tile 8) ----
        floatx4 accg = zf;
#pragma unroll
        for (int ks = 0; ks < 4; ++ks) {
            const short8 bf = *(const short8*)(WC1X + (8 * 16 + lr) * 136 + ks * 32 + lg * 8);
            accg = __builtin_amdgcn_mfma_f32_16x16x32_bf16(af2[ks], bf, accg, 0, 0, 0);
        }
        float t4[4];
#pragma unroll
        for (int r = 0; r < 4; ++r) {
            const float ep  = __shfl(accg[r], l & 48);
            const float ajr = __shfl(adjv, (l & 48) | (lg * 4 + r));
            t4[r] = sigm_f(ep) * ajr;
        }
        // message partial — acc1 dies here
#pragma unroll
        for (int nt = 0; nt < 8; ++nt)
            msg[nt] += acc1[nt][0] * t4[0] + acc1[nt][1] * t4[1]
                     + acc1[nt][2] * t4[2] + acc1[nt][3] * t4[3];

        // ---- GEMM2 phi tiles, streamed one accumulator at a time ----
        float ph[4] = {0.f, 0.f, 0.f, 0.f};
#pragma unroll
        for (int nt = 0; nt < 8; ++nt) {
            floatx4 acc2 = zf;
#pragma unroll
            for (int ks = 0; ks < 4; ++ks) {
                const short8 bf = *(const short8*)(WC1X + (nt * 16 + lr) * 136 + ks * 32 + lg * 8);
                acc2 = __builtin_amdgcn_mfma_f32_16x16x32_bf16(af2[ks], bf, acc2, 0, 0, 0);
            }
#pragma unroll
            for (int r = 0; r < 4; ++r)
                ph[r] = fmaf(silu_f(acc2[r]), wc2v[nt], ph[r]);
        }
#pragma unroll
        for (int msk = 1; msk <= 8; msk <<= 1)
#pragma unroll
            for (int r = 0; r < 4; ++r)
                ph[r] += __shfl_xor(ph[r], msk);
        // gather phi for this lane's own edge jj
        const int src = ((lr >> 2) << 4) | lr;
        const float q0 = __shfl(ph[0], src), q1 = __shfl(ph[1], src);
        const float q2 = __shfl(ph[2], src), q3 = __shfl(ph[3], src);
        const int rr = lr & 3;
        const float phl = rr == 0 ? q0 : rr == 1 ? q1 : rr == 2 ? q2 : q3;
        const float pm = phl * vm;
        px = fmaf(vnx, pm, px); py = fmaf(vny, pm, py); pz = fmaf(vnz, pm, pz);
    }

    // ---- epilogue (register reductions, no LDS) ----
#pragma unroll
    for (int msk = 16; msk <= 32; msk <<= 1)
#pragma unroll
        for (int nt = 0; nt < 8; ++nt)
            msg[nt] += __shfl_xor(msg[nt], msk);
    if (l < 16) {
#pragma unroll
        for (int nt = 0; nt < 8; ++nt)
            msg_ws[((size_t)(b * N_ + i)) * H_ + nt * 16 + l] = msg[nt];
    }
#pragma unroll
    for (int msk = 1; msk <= 8; msk <<= 1) {
        px += __shfl_xor(px, msk);
        py += __shfl_xor(py, msk);
        pz += __shfl_xor(pz, msk);
    }
    if (l == 0) {
        const size_t o = ((size_t)(b * N_ + i)) * 3;
        pos_out[o + 0] = pos[o + 0] + cinv * px;
        pos_out[o + 1] = pos[o + 1] + cinv * py;
        pos_out[o + 2] = pos[o + 2] + cinv * pz;
    }
}

// ---------------- k3: node MLP ----------------
__global__ __launch_bounds__(128) void k3_node(
        const float* __restrict__ nf,
        const float* __restrict__ Wn1,
        const float* __restrict__ Wn2,
        const float* __restrict__ msg_ws,
        float* __restrict__ out) {
    const int b  = blockIdx.x >> 4;
    const int r0 = (blockIdx.x & 15) << 3;
    const int h  = threadIdx.x;
    __shared__ float in_s[8][256];
    __shared__ float t_s[8][128];
#pragma unroll
    for (int r = 0; r < 8; ++r) {
        in_s[r][h]       = nf[((size_t)(b * N_ + r0 + r)) * NF_ + h];
        in_s[r][128 + h] = msg_ws[((size_t)(b * N_ + r0 + r)) * H_ + h];
    }
    __syncthreads();
    float acc[8];
#pragma unroll
    for (int r = 0; r < 8; ++r) acc[r] = 0.f;
    for (int c = 0; c < 256; ++c) {
        const float wv = Wn1[c * H_ + h];
#pragma unroll
        for (int r = 0; r < 8; ++r) acc[r] = fmaf(in_s[r][c], wv, acc[r]);
    }
#pragma unroll
    for (int r = 0; r < 8; ++r) t_s[r][h] = silu_f(acc[r]);
    __syncthreads();
    float o[8];
#pragma unroll
    for (int r = 0; r < 8; ++r) o[r] = 0.f;
    for (int c = 0; c < 128; ++c) {
        const float wv = Wn2[c * NF_ + h];
#pragma unroll
        for (int r = 0; r < 8; ++r) o[r] = fmaf(t_s[r][c], wv, o[r]);
    }
#pragma unroll
    for (int r = 0; r < 8; ++r)
        out[((size_t)(b * N_ + r0 + r)) * NF_ + h] = in_s[r][h] + o[r];
}

extern "C" void kernel_launch(void* const* d_in, const int* in_sizes, int n_in,
                              void* d_out, int out_size, void* d_ws, size_t ws_size,
                              hipStream_t stream) {
    const float* node_feat = (const float*)d_in[0];
    const float* pos   = (const float*)d_in[1];
    const float* valid = (const float*)d_in[2];
    const float* adj   = (const float*)d_in[3];
    const float* We1   = (const float*)d_in[4];
    const float* We2   = (const float*)d_in[5];
    const float* Wc1   = (const float*)d_in[6];
    const float* Wc2   = (const float*)d_in[7];
    const float* Wn1   = (const float*)d_in[8];
    const float* Wn2   = (const float*)d_in[9];
    const float* Wi    = (const float*)d_in[10];

    float* out     = (float*)d_out;
    float* pos_out = out + (size_t)B_ * N_ * NF_;

    const size_t node_elems = (size_t)B_ * N_ * H_;
    if (ws_size < (3 * node_elems + B_) * sizeof(float)) return;
    float* A_ws   = (float*)d_ws;
    float* Bm_ws  = A_ws + node_elems;
    float* msg_ws = Bm_ws + node_elems;
    float* Cinv   = msg_ws + node_elems;

    k1_pre<<<B_ * 16, 128, 0, stream>>>(node_feat, We1, A_ws, Bm_ws);
    kC<<<B_, 64, 0, stream>>>(valid, Cinv);
    k2_edge<<<B_ * 16, 512, 0, stream>>>(pos, valid, adj, We1, We2, Wc1, Wc2, Wi,
                                         A_ws, Bm_ws, Cinv, msg_ws, pos_out);
    k3_node<<<B_ * 16, 128, 0, stream>>>(node_feat, Wn1, Wn2, msg_ws, out);
}